// Round 5
// baseline (478.939 us; speedup 1.0000x reference)
//
#include <hip/hip_runtime.h>

#define HID 128
#define NPG 1000
#define NGRAPH 100
#define NNODES (NPG * NGRAPH)      // 100000
#define DEG 8
#define LN_EPS 1e-5f

// ---------------------------------------------------------------------------
// K1: h = relu(x[0:2N] @ W^T + b) via split-fp16 MFMA (3-term: hi*hi + lo*hi
// + hi*lo, fp32 accumulate -> ~2^-22 relative error, fp32-equivalent here).
// S rows (r < N) go to outS (= out), I rows (r >= N) go to outI (= d_ws when
// available).  Block 0 also zeroes the 512B sentinel row at outI[NNODES]
// (used by K2's padded-CSR gather).  ~55 us, near its 49 us roofline.
// ---------------------------------------------------------------------------
#define K1_ROWS 128

typedef _Float16 half8 __attribute__((ext_vector_type(8)));
typedef float f32x4 __attribute__((ext_vector_type(4)));

__device__ inline void cvt_split(const float4 a, const float4 b,
                                 half8& hi, half8& lo)
{
    float v[8] = {a.x, a.y, a.z, a.w, b.x, b.y, b.z, b.w};
    #pragma unroll
    for (int i = 0; i < 8; ++i) {
        _Float16 h = (_Float16)v[i];          // RNE
        hi[i] = h;
        lo[i] = (_Float16)(v[i] - (float)h);  // remainder exact in f32
    }
}

__global__ __launch_bounds__(256, 2) void k_gemm_relu(
    const float* __restrict__ x, const float* __restrict__ W,
    const float* __restrict__ bias, float* __restrict__ outS,
    float* __restrict__ outI, float* __restrict__ zrow, int nrows)
{
    __shared__ alignas(16) _Float16 Xh[K1_ROWS * 64];
    __shared__ alignas(16) _Float16 Xl[K1_ROWS * 64];
    __shared__ alignas(16) _Float16 Wh[HID * 64];
    __shared__ alignas(16) _Float16 Wl[HID * 64];

    const int tid  = threadIdx.x;
    const int lane = tid & 63;
    const int w    = tid >> 6;
    const int wr   = (w >> 1) * 64;   // wave row offset in tile
    const int wc   = (w & 1) * 64;    // wave col offset
    const int r0   = blockIdx.x * K1_ROWS;

    if (zrow != nullptr && blockIdx.x == 0 && tid < HID) zrow[tid] = 0.f;

    f32x4 acc[4][4];
    #pragma unroll
    for (int i = 0; i < 4; ++i)
        #pragma unroll
        for (int j = 0; j < 4; ++j)
            acc[i][j] = (f32x4){0.f, 0.f, 0.f, 0.f};

    const int l15 = lane & 15;
    const int lg  = lane >> 4;       // k-group 0..3
    const int swz = (lane & 7) << 3; // row&7 == lane&7 for all frag rows/cols

    for (int kh = 0; kh < 2; ++kh) {
        if (kh) __syncthreads();

        // ---- stage X half-tile: 128 rows x 64 k, fp32 -> (hi,lo) f16 ----
        #pragma unroll
        for (int it = 0; it < 4; ++it) {
            int chunk = tid + it * 256;      // 1024 chunks of 8 halves
            int row = chunk >> 3, kg = chunk & 7;
            const float* gp = &x[(size_t)(r0 + row) * HID + kh * 64 + kg * 8];
            float4 a = reinterpret_cast<const float4*>(gp)[0];
            float4 b = reinterpret_cast<const float4*>(gp)[1];
            half8 hi, lo; cvt_split(a, b, hi, lo);
            int widx = (row * 64 + kg * 8) ^ ((row & 7) << 3);
            *reinterpret_cast<half8*>(&Xh[widx]) = hi;
            *reinterpret_cast<half8*>(&Xl[widx]) = lo;
        }
        // ---- stage W half-tile: 128 out-cols x 64 k ----
        #pragma unroll
        for (int it = 0; it < 4; ++it) {
            int chunk = tid + it * 256;
            int row = chunk >> 3, kg = chunk & 7;
            const float* gp = &W[(size_t)row * HID + kh * 64 + kg * 8];
            float4 a = reinterpret_cast<const float4*>(gp)[0];
            float4 b = reinterpret_cast<const float4*>(gp)[1];
            half8 hi, lo; cvt_split(a, b, hi, lo);
            int widx = (row * 64 + kg * 8) ^ ((row & 7) << 3);
            *reinterpret_cast<half8*>(&Wh[widx]) = hi;
            *reinterpret_cast<half8*>(&Wl[widx]) = lo;
        }
        __syncthreads();

        // ---- compute: 2 kb-steps of K=32, 48 MFMA each ----
        #pragma unroll
        for (int kb = 0; kb < 2; ++kb) {
            half8 ah[4], al[4], bh[4], bl[4];
            #pragma unroll
            for (int t = 0; t < 4; ++t) {
                int arow = wr + t * 16 + l15;
                int aidx = (arow * 64 + kb * 32 + lg * 8) ^ swz;
                ah[t] = *reinterpret_cast<const half8*>(&Xh[aidx]);
                al[t] = *reinterpret_cast<const half8*>(&Xl[aidx]);
                int bcol = wc + t * 16 + l15;
                int bidx = (bcol * 64 + kb * 32 + lg * 8) ^ swz;
                bh[t] = *reinterpret_cast<const half8*>(&Wh[bidx]);
                bl[t] = *reinterpret_cast<const half8*>(&Wl[bidx]);
            }
            #pragma unroll
            for (int rt = 0; rt < 4; ++rt)
                #pragma unroll
                for (int ct = 0; ct < 4; ++ct) {
                    acc[rt][ct] = __builtin_amdgcn_mfma_f32_16x16x32_f16(
                        ah[rt], bh[ct], acc[rt][ct], 0, 0, 0);
                    acc[rt][ct] = __builtin_amdgcn_mfma_f32_16x16x32_f16(
                        al[rt], bh[ct], acc[rt][ct], 0, 0, 0);
                    acc[rt][ct] = __builtin_amdgcn_mfma_f32_16x16x32_f16(
                        ah[rt], bl[ct], acc[rt][ct], 0, 0, 0);
                }
        }
    }

    // ---- epilogue: bias + relu + store (64B-coalesced per 16-lane group) ----
    float bc[4];
    #pragma unroll
    for (int ct = 0; ct < 4; ++ct) bc[ct] = bias[wc + ct * 16 + l15];

    #pragma unroll
    for (int rt = 0; rt < 4; ++rt) {
        int rowb = r0 + wr + rt * 16 + lg * 4;
        #pragma unroll
        for (int j = 0; j < 4; ++j) {
            int r = rowb + j;
            if (r < nrows) {
                float* base = (r < NNODES)
                                  ? &outS[(size_t)r * HID]
                                  : &outI[(size_t)(r - NNODES) * HID];
                float* hp = base + wc + l15;
                #pragma unroll
                for (int ct = 0; ct < 4; ++ct)
                    hp[ct * 16] = fmaxf(acc[rt][ct][j] + bc[ct], 0.f);
            }
        }
    }
}

// ---------------------------------------------------------------------------
// K2 (fused): per-node AI gather + dS/dI/dR + LayerNorm + tail copy.
// 20 blocks/graph x 50 nodes, 256 threads (4 waves).
//
// Latency structure (round-4 was latency-bound at 33% HBM, 17% VALU):
//  - padded CSR: each node's column segment padded to a multiple of 4 with
//    sentinel index NNODES -> a zero row in ws.  Gather = branchless
//    fixed-stride rounds of 4 loads, no deg-dependent tail.
//  - 2 nodes per 32-lane half (2p, 2p+1), interleaved: common gather round
//    issues 8 independent row loads before accumulating (2x MLP); the two
//    LN shuffle chains pipeline.  Adjacent nodes -> wave covers 1-2KB
//    contiguous for S/I/tail/out rows.
//  - matched-edge compaction: pass 1 histograms AND records packed
//    (e<<6|rl) for the ~400 in-range edges; scatter iterates those only
//    (no second 16000-edge scan).  Pass-1 reads are int4.
//  - two-pass LN (exact centered variance) restores round-3 accuracy.
//
// XCD co-location: id = (bi&7)*250 + bi>>3; graph's 20 blocks contiguous on
// one XCD (96/100 graphs) -> I-slice + edges served from that XCD's L2.
// ---------------------------------------------------------------------------
#define BPG2  20
#define RPB2  50            // rows per block
#define ECAP2 768           // padded cols capacity (mean ~475)
#define MCAP  640           // matched edges capacity (mean 400, +12 sigma)

__global__ __launch_bounds__(256, 6) void k_agg_final(
    const float* __restrict__ x, const float* __restrict__ Sbuf,
    const float* __restrict__ Ibuf, const int* __restrict__ erow,
    const int* __restrict__ ecol, const float* __restrict__ lnw,
    const float* __restrict__ lnb, float* __restrict__ out)
{
    __shared__ int cnt[RPB2];
    __shared__ int st[RPB2];
    __shared__ int wp[RPB2];
    __shared__ int scn[64];
    __shared__ int cols[ECAP2];
    __shared__ int medge[MCAP];
    __shared__ int nm;

    const int bi    = blockIdx.x;
    const int id    = (bi & 7) * (NGRAPH * BPG2 / 8) + (bi >> 3);
    const int g     = id / BPG2;
    const int q     = id % BPG2;
    const int row0  = q * RPB2;
    const int nbase = g * NPG;
    const int ebase = g * (NPG * DEG);
    const int tid   = threadIdx.x;

    if (tid < RPB2) cnt[tid] = 0;
    if (tid == 0) nm = 0;
    __syncthreads();

    // pass 1: histogram + record matched edges (int4 edge reads)
    for (int e4 = tid * 4; e4 < NPG * DEG; e4 += 1024) {
        int4 rr = *reinterpret_cast<const int4*>(&erow[ebase + e4]);
        #pragma unroll
        for (int u = 0; u < 4; ++u) {
            int rv = (u == 0) ? rr.x : (u == 1) ? rr.y : (u == 2) ? rr.z : rr.w;
            int rl = rv - nbase - row0;
            if ((unsigned)rl < (unsigned)RPB2) {
                atomicAdd(&cnt[rl], 1);
                int i = atomicAdd(&nm, 1);
                if (i < MCAP) medge[i] = ((e4 + u) << 6) | rl;
            }
        }
    }
    __syncthreads();

    // padded counts (multiple of 4, min 4) -> inclusive scan over 64
    int pcv = 0;
    if (tid < RPB2) { int c = cnt[tid]; pcv = (c + 3) & ~3; if (pcv < 4) pcv = 4; }
    if (tid < 64) scn[tid] = pcv;
    __syncthreads();
    #pragma unroll
    for (int s = 1; s < 64; s <<= 1) {
        int t = (tid < 64 && tid >= s) ? scn[tid - s] : 0;
        __syncthreads();
        if (tid < 64) scn[tid] += t;
        __syncthreads();
    }
    if (tid < RPB2) { int e0 = scn[tid] - pcv; st[tid] = e0; wp[tid] = e0; }
    __syncthreads();

    // scatter matched edges only
    const int nmc = (nm < MCAP) ? nm : MCAP;
    for (int i = tid; i < nmc; i += 256) {
        int pk = medge[i];
        int e  = pk >> 6, rl = pk & 63;
        int p  = atomicAdd(&wp[rl], 1);
        if (p < ECAP2) cols[p] = ecol[ebase + e];
    }
    __syncthreads();

    // sentinel-pad each segment to its padded length
    if (tid < RPB2) {
        int p  = wp[tid];                 // == st + cnt
        int e1 = st[tid] + pcv;
        for (; p < e1 && p < ECAP2; ++p) cols[p] = NNODES;  // -> zero row
    }
    __syncthreads();

    const int wave = tid >> 6, lane = tid & 63;
    const int h    = lane >> 5;
    const int hw   = (wave << 1) | h;     // half-wave id 0..7
    const int l32  = lane & 31;
    const int c4   = l32 * 4;
    const size_t N = NNODES;

    const float4 lwv = *reinterpret_cast<const float4*>(&lnw[c4]);
    const float4 lbv = *reinterpret_cast<const float4*>(&lnb[c4]);

    // two-pass LN for two nodes, chains interleaved (pipeline in DS unit)
    auto ln2 = [&](float4 a, float4 b, float* da, float* db, bool vA, bool vB) {
        float sA = a.x + a.y + a.z + a.w;
        float sB = b.x + b.y + b.z + b.w;
        #pragma unroll
        for (int m = 1; m < 32; m <<= 1) {
            sA += __shfl_xor(sA, m);
            sB += __shfl_xor(sB, m);
        }
        const float mA = sA * (1.f / 128.f), mB = sB * (1.f / 128.f);
        float qA = (a.x-mA)*(a.x-mA) + (a.y-mA)*(a.y-mA)
                 + (a.z-mA)*(a.z-mA) + (a.w-mA)*(a.w-mA);
        float qB = (b.x-mB)*(b.x-mB) + (b.y-mB)*(b.y-mB)
                 + (b.z-mB)*(b.z-mB) + (b.w-mB)*(b.w-mB);
        #pragma unroll
        for (int m = 1; m < 32; m <<= 1) {
            qA += __shfl_xor(qA, m);
            qB += __shfl_xor(qB, m);
        }
        const float rsA = rsqrtf(qA * (1.f / 128.f) + LN_EPS);
        const float rsB = rsqrtf(qB * (1.f / 128.f) + LN_EPS);
        if (vA) {
            float4 o;
            o.x = (a.x - mA) * rsA * lwv.x + lbv.x;
            o.y = (a.y - mA) * rsA * lwv.y + lbv.y;
            o.z = (a.z - mA) * rsA * lwv.z + lbv.z;
            o.w = (a.w - mA) * rsA * lwv.w + lbv.w;
            *reinterpret_cast<float4*>(da) = o;
        }
        if (vB) {
            float4 o;
            o.x = (b.x - mB) * rsB * lwv.x + lbv.x;
            o.y = (b.y - mB) * rsB * lwv.y + lbv.y;
            o.z = (b.z - mB) * rsB * lwv.z + lbv.z;
            o.w = (b.w - mB) * rsB * lwv.w + lbv.w;
            *reinterpret_cast<float4*>(db) = o;
        }
    };

    #pragma unroll 1
    for (int k = 0; k < 4; ++k) {
        const int p  = k * 8 + hw;        // pair index, < 25 valid
        const int nA = 2 * p, nB = 2 * p + 1;
        const bool vA = (nA < RPB2), vB = (nB < RPB2);

        int stA = 0, rA = 0, stB = 0, rB = 0;
        if (vA) {
            int c = cnt[nA]; int pc = (c + 3) & ~3; if (pc < 4) pc = 4;
            stA = st[nA];
            rA  = (stA < ECAP2) ? min(pc >> 2, (ECAP2 - stA) >> 2) : 0;
        }
        if (vB) {
            int c = cnt[nB]; int pc = (c + 3) & ~3; if (pc < 4) pc = 4;
            stB = st[nB];
            rB  = (stB < ECAP2) ? min(pc >> 2, (ECAP2 - stB) >> 2) : 0;
        }

        const size_t gA = (size_t)(nbase + row0 + (vA ? nA : 0));
        const size_t gB = (size_t)(nbase + row0 + (vB ? nB : 0));

        // own-row loads issued up front (independent of gather)
        float4 SvA = *reinterpret_cast<const float4*>(&Sbuf[gA * HID + c4]);
        float4 IvA = *reinterpret_cast<const float4*>(&Ibuf[gA * HID + c4]);
        float4 TA  = *reinterpret_cast<const float4*>(&x[(3 * N + gA) * HID + c4]);
        float4 SvB = *reinterpret_cast<const float4*>(&Sbuf[gB * HID + c4]);
        float4 IvB = *reinterpret_cast<const float4*>(&Ibuf[gB * HID + c4]);
        float4 TB  = *reinterpret_cast<const float4*>(&x[(3 * N + gB) * HID + c4]);

        float axA = 0.f, ayA = 0.f, azA = 0.f, awA = 0.f;
        float axB = 0.f, ayB = 0.f, azB = 0.f, awB = 0.f;
        int jA = stA, jB = stB;
        const int cmn = (rA < rB) ? rA : rB;

        #pragma unroll 1
        for (int r = 0; r < cmn; ++r) {
            int a0 = cols[jA], a1 = cols[jA+1], a2 = cols[jA+2], a3 = cols[jA+3];
            int b0 = cols[jB], b1 = cols[jB+1], b2 = cols[jB+2], b3 = cols[jB+3];
            float4 u0 = *reinterpret_cast<const float4*>(&Ibuf[(size_t)a0 * HID + c4]);
            float4 u1 = *reinterpret_cast<const float4*>(&Ibuf[(size_t)a1 * HID + c4]);
            float4 u2 = *reinterpret_cast<const float4*>(&Ibuf[(size_t)a2 * HID + c4]);
            float4 u3 = *reinterpret_cast<const float4*>(&Ibuf[(size_t)a3 * HID + c4]);
            float4 w0 = *reinterpret_cast<const float4*>(&Ibuf[(size_t)b0 * HID + c4]);
            float4 w1 = *reinterpret_cast<const float4*>(&Ibuf[(size_t)b1 * HID + c4]);
            float4 w2 = *reinterpret_cast<const float4*>(&Ibuf[(size_t)b2 * HID + c4]);
            float4 w3 = *reinterpret_cast<const float4*>(&Ibuf[(size_t)b3 * HID + c4]);
            axA += u0.x + u1.x + u2.x + u3.x;
            ayA += u0.y + u1.y + u2.y + u3.y;
            azA += u0.z + u1.z + u2.z + u3.z;
            awA += u0.w + u1.w + u2.w + u3.w;
            axB += w0.x + w1.x + w2.x + w3.x;
            ayB += w0.y + w1.y + w2.y + w3.y;
            azB += w0.z + w1.z + w2.z + w3.z;
            awB += w0.w + w1.w + w2.w + w3.w;
            jA += 4; jB += 4;
        }
        #pragma unroll 1
        for (int r = cmn; r < rA; ++r) {
            int a0 = cols[jA], a1 = cols[jA+1], a2 = cols[jA+2], a3 = cols[jA+3];
            float4 u0 = *reinterpret_cast<const float4*>(&Ibuf[(size_t)a0 * HID + c4]);
            float4 u1 = *reinterpret_cast<const float4*>(&Ibuf[(size_t)a1 * HID + c4]);
            float4 u2 = *reinterpret_cast<const float4*>(&Ibuf[(size_t)a2 * HID + c4]);
            float4 u3 = *reinterpret_cast<const float4*>(&Ibuf[(size_t)a3 * HID + c4]);
            axA += u0.x + u1.x + u2.x + u3.x;
            ayA += u0.y + u1.y + u2.y + u3.y;
            azA += u0.z + u1.z + u2.z + u3.z;
            awA += u0.w + u1.w + u2.w + u3.w;
            jA += 4;
        }
        #pragma unroll 1
        for (int r = cmn; r < rB; ++r) {
            int b0 = cols[jB], b1 = cols[jB+1], b2 = cols[jB+2], b3 = cols[jB+3];
            float4 w0 = *reinterpret_cast<const float4*>(&Ibuf[(size_t)b0 * HID + c4]);
            float4 w1 = *reinterpret_cast<const float4*>(&Ibuf[(size_t)b1 * HID + c4]);
            float4 w2 = *reinterpret_cast<const float4*>(&Ibuf[(size_t)b2 * HID + c4]);
            float4 w3 = *reinterpret_cast<const float4*>(&Ibuf[(size_t)b3 * HID + c4]);
            axB += w0.x + w1.x + w2.x + w3.x;
            ayB += w0.y + w1.y + w2.y + w3.y;
            azB += w0.z + w1.z + w2.z + w3.z;
            awB += w0.w + w1.w + w2.w + w3.w;
            jB += 4;
        }

        // beta/gam = cols 0,1 of tail row = each half's lane 0 (lane h*32)
        const float betaA = __shfl(TA.x, h << 5);
        const float gamA  = __shfl(TA.y, h << 5);
        const float betaB = __shfl(TB.x, h << 5);
        const float gamB  = __shfl(TB.y, h << 5);

        float4 dSA, dIA, dRA, dSB, dIB, dRB;
        dSA.x = -betaA * (axA * SvA.x);  dSB.x = -betaB * (axB * SvB.x);
        dSA.y = -betaA * (ayA * SvA.y);  dSB.y = -betaB * (ayB * SvB.y);
        dSA.z = -betaA * (azA * SvA.z);  dSB.z = -betaB * (azB * SvB.z);
        dSA.w = -betaA * (awA * SvA.w);  dSB.w = -betaB * (awB * SvB.w);
        dIA.x = -dSA.x - gamA * IvA.x;   dIB.x = -dSB.x - gamB * IvB.x;
        dIA.y = -dSA.y - gamA * IvA.y;   dIB.y = -dSB.y - gamB * IvB.y;
        dIA.z = -dSA.z - gamA * IvA.z;   dIB.z = -dSB.z - gamB * IvB.z;
        dIA.w = -dSA.w - gamA * IvA.w;   dIB.w = -dSB.w - gamB * IvB.w;
        dRA.x = gamA * IvA.x;            dRB.x = gamB * IvB.x;
        dRA.y = gamA * IvA.y;            dRB.y = gamB * IvB.y;
        dRA.z = gamA * IvA.z;            dRB.z = gamB * IvB.z;
        dRA.w = gamA * IvA.w;            dRB.w = gamB * IvB.w;

        ln2(dSA, dSB, &out[gA * HID + c4],           &out[gB * HID + c4],           vA, vB);
        ln2(dIA, dIB, &out[(N + gA) * HID + c4],     &out[(N + gB) * HID + c4],     vA, vB);
        ln2(dRA, dRB, &out[(2 * N + gA) * HID + c4], &out[(2 * N + gB) * HID + c4], vA, vB);
        if (vA) *reinterpret_cast<float4*>(&out[(3 * N + gA) * HID + c4]) = TA;
        if (vB) *reinterpret_cast<float4*>(&out[(3 * N + gB) * HID + c4]) = TB;
    }
}

// ---------------------------------------------------------------------------
// Fallback path (ws too small): original K2 (AI materialized) + K3.
// ---------------------------------------------------------------------------
#define BPG  8
#define RPB  (NPG / BPG)    // 125
#define ECAP 1280

__global__ __launch_bounds__(256) void k_aggregate(
    const float* __restrict__ I, const int* __restrict__ erow,
    const int* __restrict__ ecol, float* __restrict__ AI)
{
    __shared__ int cnt[RPB];
    __shared__ int wp[RPB];
    __shared__ int scan[256];
    __shared__ int cols[ECAP];

    const int g     = blockIdx.x / BPG;
    const int q     = blockIdx.x % BPG;
    const int row0  = q * RPB;
    const int nbase = g * NPG;
    const int ebase = g * (NPG * DEG);
    const int tid   = threadIdx.x;

    if (tid < RPB) cnt[tid] = 0;
    __syncthreads();

    for (int e = tid; e < NPG * DEG; e += 256) {
        int rl = erow[ebase + e] - nbase - row0;
        if ((unsigned)rl < (unsigned)RPB) atomicAdd(&cnt[rl], 1);
    }
    __syncthreads();

    int v = (tid < RPB) ? cnt[tid] : 0;
    scan[tid] = v;
    __syncthreads();
    #pragma unroll
    for (int s = 1; s < 256; s <<= 1) {
        int t = (tid >= s) ? scan[tid - s] : 0;
        __syncthreads();
        scan[tid] += t;
        __syncthreads();
    }
    if (tid < RPB) wp[tid] = scan[tid] - cnt[tid];
    __syncthreads();

    for (int e = tid; e < NPG * DEG; e += 256) {
        int rl = erow[ebase + e] - nbase - row0;
        if ((unsigned)rl < (unsigned)RPB) {
            int p = atomicAdd(&wp[rl], 1);
            if (p < ECAP) cols[p] = ecol[ebase + e];
        }
    }
    __syncthreads();

    const int wave = tid >> 6, lane = tid & 63;
    const int c = lane * 2;
    for (int n = wave; n < RPB; n += 4) {
        int deg = cnt[n];
        int end = wp[n];
        int j   = end - deg;
        float ax = 0.f, ay = 0.f;
        for (; j + 4 <= end; j += 4) {
            int c0 = cols[j], c1 = cols[j + 1], c2 = cols[j + 2], c3 = cols[j + 3];
            float2 v0 = *reinterpret_cast<const float2*>(&I[(size_t)c0 * HID + c]);
            float2 v1 = *reinterpret_cast<const float2*>(&I[(size_t)c1 * HID + c]);
            float2 v2 = *reinterpret_cast<const float2*>(&I[(size_t)c2 * HID + c]);
            float2 v3 = *reinterpret_cast<const float2*>(&I[(size_t)c3 * HID + c]);
            ax += v0.x + v1.x + v2.x + v3.x;
            ay += v0.y + v1.y + v2.y + v3.y;
        }
        for (; j < end; j++) {
            float2 v0 = *reinterpret_cast<const float2*>(&I[(size_t)cols[j] * HID + c]);
            ax += v0.x; ay += v0.y;
        }
        float2 o; o.x = ax; o.y = ay;
        *reinterpret_cast<float2*>(&AI[(size_t)(nbase + row0 + n) * HID + c]) = o;
    }
}

__global__ __launch_bounds__(256) void k_final(
    const float* __restrict__ x, const float* __restrict__ lnw,
    const float* __restrict__ lnb, float* __restrict__ out)
{
    const int wave = threadIdx.x >> 6;
    const int lane = threadIdx.x & 63;
    const size_t i = (size_t)blockIdx.x * 4 + wave;
    const int c    = lane * 2;
    const size_t N = NNODES;

    float2 S  = *reinterpret_cast<const float2*>(&out[i * HID + c]);
    float2 I2 = *reinterpret_cast<const float2*>(&out[(N + i) * HID + c]);
    float2 A  = *reinterpret_cast<const float2*>(&out[(2 * N + i) * HID + c]);

    const float beta = x[(3 * N + i) * HID + 0];
    const float gam  = x[(3 * N + i) * HID + 1];

    float2 dS, dI, dR;
    dS.x = -beta * (A.x * S.x);
    dS.y = -beta * (A.y * S.y);
    dI.x = -dS.x - gam * I2.x;
    dI.y = -dS.y - gam * I2.y;
    dR.x = gam * I2.x;
    dR.y = gam * I2.y;

    const float2 lw = *reinterpret_cast<const float2*>(&lnw[c]);
    const float2 lb = *reinterpret_cast<const float2*>(&lnb[c]);

    auto ln_store = [&](float2 v, float* dst) {
        float s = v.x + v.y;
        #pragma unroll
        for (int m = 1; m < 64; m <<= 1) s += __shfl_xor(s, m);
        const float mean = s * (1.f / 128.f);
        const float dx = v.x - mean, dy = v.y - mean;
        float q = dx * dx + dy * dy;
        #pragma unroll
        for (int m = 1; m < 64; m <<= 1) q += __shfl_xor(q, m);
        const float rs = rsqrtf(q * (1.f / 128.f) + LN_EPS);
        float2 o;
        o.x = dx * rs * lw.x + lb.x;
        o.y = dy * rs * lw.y + lb.y;
        *reinterpret_cast<float2*>(dst) = o;
    };

    ln_store(dS, &out[i * HID + c]);
    ln_store(dI, &out[(N + i) * HID + c]);
    ln_store(dR, &out[(2 * N + i) * HID + c]);

    const float2 t2 =
        *reinterpret_cast<const float2*>(&x[(3 * N + i) * HID + c]);
    *reinterpret_cast<float2*>(&out[(3 * N + i) * HID + c]) = t2;
}

// ---------------------------------------------------------------------------
extern "C" void kernel_launch(void* const* d_in, const int* in_sizes, int n_in,
                              void* d_out, int out_size, void* d_ws,
                              size_t ws_size, hipStream_t stream)
{
    // inputs: 0:t 1:x 2:edge_row 3:edge_col 4:W 5:b 6:ln_w 7:ln_b
    const float* x   = (const float*)d_in[1];
    const int* erow  = (const int*)d_in[2];
    const int* ecol  = (const int*)d_in[3];
    const float* W   = (const float*)d_in[4];
    const float* b   = (const float*)d_in[5];
    const float* lnw = (const float*)d_in[6];
    const float* lnb = (const float*)d_in[7];
    float* out = (float*)d_out;

    const int nrows = 2 * NNODES;                    // R rows never needed
    const size_t ineed = ((size_t)NNODES + 1) * HID * sizeof(float); // I + zrow

    if (d_ws != nullptr && ws_size >= ineed) {
        // Fused path: I rows -> workspace (+ sentinel zero row).
        float* Iws  = (float*)d_ws;
        float* zrow = Iws + (size_t)NNODES * HID;
        k_gemm_relu<<<(nrows + K1_ROWS - 1) / K1_ROWS, 256, 0, stream>>>(
            x, W, b, out, Iws, zrow, nrows);
        k_agg_final<<<NGRAPH * BPG2, 256, 0, stream>>>(
            x, out, Iws, erow, ecol, lnw, lnb, out);
    } else {
        // Fallback: original 3-kernel path, I rows in out[N..2N).
        float* Iptr  = out + (size_t)NNODES * HID;
        float* AIptr = out + (size_t)2 * NNODES * HID;
        k_gemm_relu<<<(nrows + K1_ROWS - 1) / K1_ROWS, 256, 0, stream>>>(
            x, W, b, out, Iptr, nullptr, nrows);
        k_aggregate<<<NGRAPH * BPG, 256, 0, stream>>>(Iptr, erow, ecol, AIptr);
        k_final<<<NNODES / 4, 256, 0, stream>>>(x, lnw, lnb, out);
    }
}

// Round 6
// 453.663 us; speedup vs baseline: 1.0557x; 1.0557x over previous
//
#include <hip/hip_runtime.h>

#define HID 128
#define NPG 1000
#define NGRAPH 100
#define NNODES (NPG * NGRAPH)      // 100000
#define DEG 8
#define LN_EPS 1e-5f

// ---------------------------------------------------------------------------
// K1: h = relu(x[0:2N] @ W^T + b) via split-fp16 MFMA (3-term: hi*hi + lo*hi
// + hi*lo, fp32 accumulate -> ~2^-22 relative error, fp32-equivalent here).
// S rows (r < N) -> outS (= out), I rows (r >= N) -> outI (= d_ws) so the
// fused K2 can overwrite out[N..2N) with ln(dI) without racing I-gathers.
// ~55 us, near its 49 us roofline.
// ---------------------------------------------------------------------------
#define K1_ROWS 128

typedef _Float16 half8 __attribute__((ext_vector_type(8)));
typedef float f32x4 __attribute__((ext_vector_type(4)));

__device__ inline void cvt_split(const float4 a, const float4 b,
                                 half8& hi, half8& lo)
{
    float v[8] = {a.x, a.y, a.z, a.w, b.x, b.y, b.z, b.w};
    #pragma unroll
    for (int i = 0; i < 8; ++i) {
        _Float16 h = (_Float16)v[i];          // RNE
        hi[i] = h;
        lo[i] = (_Float16)(v[i] - (float)h);  // remainder exact in f32
    }
}

__global__ __launch_bounds__(256, 2) void k_gemm_relu(
    const float* __restrict__ x, const float* __restrict__ W,
    const float* __restrict__ bias, float* __restrict__ outS,
    float* __restrict__ outI, int nrows)
{
    __shared__ alignas(16) _Float16 Xh[K1_ROWS * 64];
    __shared__ alignas(16) _Float16 Xl[K1_ROWS * 64];
    __shared__ alignas(16) _Float16 Wh[HID * 64];
    __shared__ alignas(16) _Float16 Wl[HID * 64];

    const int tid  = threadIdx.x;
    const int lane = tid & 63;
    const int w    = tid >> 6;
    const int wr   = (w >> 1) * 64;   // wave row offset in tile
    const int wc   = (w & 1) * 64;    // wave col offset
    const int r0   = blockIdx.x * K1_ROWS;

    f32x4 acc[4][4];
    #pragma unroll
    for (int i = 0; i < 4; ++i)
        #pragma unroll
        for (int j = 0; j < 4; ++j)
            acc[i][j] = (f32x4){0.f, 0.f, 0.f, 0.f};

    const int l15 = lane & 15;
    const int lg  = lane >> 4;       // k-group 0..3
    const int swz = (lane & 7) << 3; // row&7 == lane&7 for all frag rows/cols

    for (int kh = 0; kh < 2; ++kh) {
        if (kh) __syncthreads();

        // ---- stage X half-tile: 128 rows x 64 k, fp32 -> (hi,lo) f16 ----
        #pragma unroll
        for (int it = 0; it < 4; ++it) {
            int chunk = tid + it * 256;      // 1024 chunks of 8 halves
            int row = chunk >> 3, kg = chunk & 7;
            const float* gp = &x[(size_t)(r0 + row) * HID + kh * 64 + kg * 8];
            float4 a = reinterpret_cast<const float4*>(gp)[0];
            float4 b = reinterpret_cast<const float4*>(gp)[1];
            half8 hi, lo; cvt_split(a, b, hi, lo);
            int widx = (row * 64 + kg * 8) ^ ((row & 7) << 3);
            *reinterpret_cast<half8*>(&Xh[widx]) = hi;
            *reinterpret_cast<half8*>(&Xl[widx]) = lo;
        }
        // ---- stage W half-tile: 128 out-cols x 64 k ----
        #pragma unroll
        for (int it = 0; it < 4; ++it) {
            int chunk = tid + it * 256;
            int row = chunk >> 3, kg = chunk & 7;
            const float* gp = &W[(size_t)row * HID + kh * 64 + kg * 8];
            float4 a = reinterpret_cast<const float4*>(gp)[0];
            float4 b = reinterpret_cast<const float4*>(gp)[1];
            half8 hi, lo; cvt_split(a, b, hi, lo);
            int widx = (row * 64 + kg * 8) ^ ((row & 7) << 3);
            *reinterpret_cast<half8*>(&Wh[widx]) = hi;
            *reinterpret_cast<half8*>(&Wl[widx]) = lo;
        }
        __syncthreads();

        // ---- compute: 2 kb-steps of K=32, 48 MFMA each ----
        #pragma unroll
        for (int kb = 0; kb < 2; ++kb) {
            half8 ah[4], al[4], bh[4], bl[4];
            #pragma unroll
            for (int t = 0; t < 4; ++t) {
                int arow = wr + t * 16 + l15;
                int aidx = (arow * 64 + kb * 32 + lg * 8) ^ swz;
                ah[t] = *reinterpret_cast<const half8*>(&Xh[aidx]);
                al[t] = *reinterpret_cast<const half8*>(&Xl[aidx]);
                int bcol = wc + t * 16 + l15;
                int bidx = (bcol * 64 + kb * 32 + lg * 8) ^ swz;
                bh[t] = *reinterpret_cast<const half8*>(&Wh[bidx]);
                bl[t] = *reinterpret_cast<const half8*>(&Wl[bidx]);
            }
            #pragma unroll
            for (int rt = 0; rt < 4; ++rt)
                #pragma unroll
                for (int ct = 0; ct < 4; ++ct) {
                    acc[rt][ct] = __builtin_amdgcn_mfma_f32_16x16x32_f16(
                        ah[rt], bh[ct], acc[rt][ct], 0, 0, 0);
                    acc[rt][ct] = __builtin_amdgcn_mfma_f32_16x16x32_f16(
                        al[rt], bh[ct], acc[rt][ct], 0, 0, 0);
                    acc[rt][ct] = __builtin_amdgcn_mfma_f32_16x16x32_f16(
                        ah[rt], bl[ct], acc[rt][ct], 0, 0, 0);
                }
        }
    }

    // ---- epilogue: bias + relu + store (64B-coalesced per 16-lane group) ----
    float bc[4];
    #pragma unroll
    for (int ct = 0; ct < 4; ++ct) bc[ct] = bias[wc + ct * 16 + l15];

    #pragma unroll
    for (int rt = 0; rt < 4; ++rt) {
        int rowb = r0 + wr + rt * 16 + lg * 4;
        #pragma unroll
        for (int j = 0; j < 4; ++j) {
            int r = rowb + j;
            if (r < nrows) {
                float* base = (r < NNODES)
                                  ? &outS[(size_t)r * HID]
                                  : &outI[(size_t)(r - NNODES) * HID];
                float* hp = base + wc + l15;
                #pragma unroll
                for (int ct = 0; ct < 4; ++ct)
                    hp[ct * 16] = fmaxf(acc[rt][ct][j] + bc[ct], 0.f);
            }
        }
    }
}

// ---------------------------------------------------------------------------
// K2 (fused): per-node AI gather + dS/dI/dR + LayerNorm + tail copy.
// 20 blocks/graph x 50 nodes, 256 threads (4 waves), R4 skeleton + 3 fixes:
//
//  - single-pass prologue: fixed 28-slot segments cols[50][28] (deg ~
//    Bin(8000,1e-3): mean 8, 28 = +7 sigma), direct atomicAdd scatter.
//    No histogram pass, no Hillis-Steele scan, no second edge scan.
//  - fused ln3: the three LayerNorms' shuffle reductions run together
//    (3 pipelined chains): 10 shfl rounds total vs 15, and exact two-pass
//    centered variance (absmax back to 0.03125).
//  - 8-deep gather batches: two 4-load groups issued before accumulating
//    (2x in-flight rows per stream).  launch_bounds(256,6) -> 85-VGPR
//    budget, peak live ~71: no spill (R5's regression was spill traffic:
//    WRITE_SIZE 200->275 MB; watch that counter).
//
// XCD co-location: id = (bi&7)*250 + bi>>3; graph's 20 blocks contiguous on
// one XCD (96/100 graphs) -> I-slice + edges served from that XCD's L2.
// ---------------------------------------------------------------------------
#define BPG2  20
#define RPB2  50            // rows per block
#define SCAP  28            // per-node column slots

__global__ __launch_bounds__(256, 6) void k_agg_final(
    const float* __restrict__ x, const float* __restrict__ Sbuf,
    const float* __restrict__ Ibuf, const int* __restrict__ erow,
    const int* __restrict__ ecol, const float* __restrict__ lnw,
    const float* __restrict__ lnb, float* __restrict__ out)
{
    __shared__ int cnt[RPB2];
    __shared__ int cols[RPB2 * SCAP];

    const int bi    = blockIdx.x;
    const int id    = (bi & 7) * (NGRAPH * BPG2 / 8) + (bi >> 3);
    const int g     = id / BPG2;
    const int q     = id % BPG2;
    const int row0  = q * RPB2;
    const int nbase = g * NPG;
    const int ebase = g * (NPG * DEG);
    const int tid   = threadIdx.x;

    if (tid < RPB2) cnt[tid] = 0;
    __syncthreads();

    // single pass: int4 erow scan, direct scatter into fixed segments
    for (int e4 = tid * 4; e4 < NPG * DEG; e4 += 1024) {
        int4 rr = *reinterpret_cast<const int4*>(&erow[ebase + e4]);
        #pragma unroll
        for (int u = 0; u < 4; ++u) {
            int rv = (u == 0) ? rr.x : (u == 1) ? rr.y : (u == 2) ? rr.z : rr.w;
            int rl = rv - nbase - row0;
            if ((unsigned)rl < (unsigned)RPB2) {
                int c = atomicAdd(&cnt[rl], 1);
                if (c < SCAP) cols[rl * SCAP + c] = ecol[ebase + e4 + u];
            }
        }
    }
    __syncthreads();

    const int wave = tid >> 6, lane = tid & 63;
    const int h    = lane >> 5;       // half-wave = node parity
    const int l32  = lane & 31;
    const int c4   = l32 * 4;         // float4 column offset
    const size_t N = NNODES;

    const float4 lwv = *reinterpret_cast<const float4*>(&lnw[c4]);
    const float4 lbv = *reinterpret_cast<const float4*>(&lnb[c4]);

    // fused 3-row LayerNorm: 3 pipelined shuffle chains, exact 2-pass var
    auto ln3 = [&](float4 a, float4 b, float4 c, size_t gn) {
        float sA = a.x + a.y + a.z + a.w;
        float sB = b.x + b.y + b.z + b.w;
        float sC = c.x + c.y + c.z + c.w;
        #pragma unroll
        for (int m = 1; m < 32; m <<= 1) {
            sA += __shfl_xor(sA, m);
            sB += __shfl_xor(sB, m);
            sC += __shfl_xor(sC, m);
        }
        const float mA = sA * (1.f / 128.f);
        const float mB = sB * (1.f / 128.f);
        const float mC = sC * (1.f / 128.f);
        float qA = (a.x-mA)*(a.x-mA) + (a.y-mA)*(a.y-mA)
                 + (a.z-mA)*(a.z-mA) + (a.w-mA)*(a.w-mA);
        float qB = (b.x-mB)*(b.x-mB) + (b.y-mB)*(b.y-mB)
                 + (b.z-mB)*(b.z-mB) + (b.w-mB)*(b.w-mB);
        float qC = (c.x-mC)*(c.x-mC) + (c.y-mC)*(c.y-mC)
                 + (c.z-mC)*(c.z-mC) + (c.w-mC)*(c.w-mC);
        #pragma unroll
        for (int m = 1; m < 32; m <<= 1) {
            qA += __shfl_xor(qA, m);
            qB += __shfl_xor(qB, m);
            qC += __shfl_xor(qC, m);
        }
        const float rsA = rsqrtf(qA * (1.f / 128.f) + LN_EPS);
        const float rsB = rsqrtf(qB * (1.f / 128.f) + LN_EPS);
        const float rsC = rsqrtf(qC * (1.f / 128.f) + LN_EPS);
        float4 o;
        o.x = (a.x - mA) * rsA * lwv.x + lbv.x;
        o.y = (a.y - mA) * rsA * lwv.y + lbv.y;
        o.z = (a.z - mA) * rsA * lwv.z + lbv.z;
        o.w = (a.w - mA) * rsA * lwv.w + lbv.w;
        *reinterpret_cast<float4*>(&out[gn * HID + c4]) = o;
        o.x = (b.x - mB) * rsB * lwv.x + lbv.x;
        o.y = (b.y - mB) * rsB * lwv.y + lbv.y;
        o.z = (b.z - mB) * rsB * lwv.z + lbv.z;
        o.w = (b.w - mB) * rsB * lwv.w + lbv.w;
        *reinterpret_cast<float4*>(&out[(N + gn) * HID + c4]) = o;
        o.x = (c.x - mC) * rsC * lwv.x + lbv.x;
        o.y = (c.y - mC) * rsC * lwv.y + lbv.y;
        o.z = (c.z - mC) * rsC * lwv.z + lbv.z;
        o.w = (c.w - mC) * rsC * lwv.w + lbv.w;
        *reinterpret_cast<float4*>(&out[(2 * N + gn) * HID + c4]) = o;
    };

    // 4 waves x 2 half-waves cover 8 nodes per sweep; all n < 50 valid
    for (int n0 = wave * 2; n0 < RPB2; n0 += 8) {
        const int n = n0 + h;
        const size_t gn = (size_t)(nbase + row0 + n);

        // own-row loads issued early (independent of the gather)
        float4 Sv = *reinterpret_cast<const float4*>(&Sbuf[gn * HID + c4]);
        float4 Iv = *reinterpret_cast<const float4*>(&Ibuf[gn * HID + c4]);
        float4 T  = *reinterpret_cast<const float4*>(&x[(3 * N + gn) * HID + c4]);

        const int deg = min(cnt[n], SCAP);
        const int* seg = &cols[n * SCAP];
        float ax = 0.f, ay = 0.f, az = 0.f, aw = 0.f;
        int j = 0;
        // 8-deep batches: 8 independent row loads in flight
        for (; j + 8 <= deg; j += 8) {
            int c0 = seg[j],   c1 = seg[j+1], c2 = seg[j+2], c3 = seg[j+3];
            int c5 = seg[j+4], c6 = seg[j+5], c7 = seg[j+6], c8 = seg[j+7];
            float4 v0 = *reinterpret_cast<const float4*>(&Ibuf[(size_t)c0 * HID + c4]);
            float4 v1 = *reinterpret_cast<const float4*>(&Ibuf[(size_t)c1 * HID + c4]);
            float4 v2 = *reinterpret_cast<const float4*>(&Ibuf[(size_t)c2 * HID + c4]);
            float4 v3 = *reinterpret_cast<const float4*>(&Ibuf[(size_t)c3 * HID + c4]);
            float4 v5 = *reinterpret_cast<const float4*>(&Ibuf[(size_t)c5 * HID + c4]);
            float4 v6 = *reinterpret_cast<const float4*>(&Ibuf[(size_t)c6 * HID + c4]);
            float4 v7 = *reinterpret_cast<const float4*>(&Ibuf[(size_t)c7 * HID + c4]);
            float4 v8 = *reinterpret_cast<const float4*>(&Ibuf[(size_t)c8 * HID + c4]);
            ax += (v0.x + v1.x) + (v2.x + v3.x) + (v5.x + v6.x) + (v7.x + v8.x);
            ay += (v0.y + v1.y) + (v2.y + v3.y) + (v5.y + v6.y) + (v7.y + v8.y);
            az += (v0.z + v1.z) + (v2.z + v3.z) + (v5.z + v6.z) + (v7.z + v8.z);
            aw += (v0.w + v1.w) + (v2.w + v3.w) + (v5.w + v6.w) + (v7.w + v8.w);
        }
        for (; j + 4 <= deg; j += 4) {
            int c0 = seg[j], c1 = seg[j+1], c2 = seg[j+2], c3 = seg[j+3];
            float4 v0 = *reinterpret_cast<const float4*>(&Ibuf[(size_t)c0 * HID + c4]);
            float4 v1 = *reinterpret_cast<const float4*>(&Ibuf[(size_t)c1 * HID + c4]);
            float4 v2 = *reinterpret_cast<const float4*>(&Ibuf[(size_t)c2 * HID + c4]);
            float4 v3 = *reinterpret_cast<const float4*>(&Ibuf[(size_t)c3 * HID + c4]);
            ax += (v0.x + v1.x) + (v2.x + v3.x);
            ay += (v0.y + v1.y) + (v2.y + v3.y);
            az += (v0.z + v1.z) + (v2.z + v3.z);
            aw += (v0.w + v1.w) + (v2.w + v3.w);
        }
        for (; j < deg; j++) {
            float4 v0 = *reinterpret_cast<const float4*>(&Ibuf[(size_t)seg[j] * HID + c4]);
            ax += v0.x; ay += v0.y; az += v0.z; aw += v0.w;
        }

        // beta/gam = cols 0,1 of tail row = this half's lane 0 (lane h*32)
        const float beta = __shfl(T.x, h << 5);
        const float gam  = __shfl(T.y, h << 5);

        float4 dS, dI, dR;
        dS.x = -beta * (ax * Sv.x);
        dS.y = -beta * (ay * Sv.y);
        dS.z = -beta * (az * Sv.z);
        dS.w = -beta * (aw * Sv.w);
        dI.x = -dS.x - gam * Iv.x;
        dI.y = -dS.y - gam * Iv.y;
        dI.z = -dS.z - gam * Iv.z;
        dI.w = -dS.w - gam * Iv.w;
        dR.x = gam * Iv.x;
        dR.y = gam * Iv.y;
        dR.z = gam * Iv.z;
        dR.w = gam * Iv.w;

        ln3(dS, dI, dR, gn);
        *reinterpret_cast<float4*>(&out[(3 * N + gn) * HID + c4]) = T;
    }
}

// ---------------------------------------------------------------------------
// Fallback path (ws too small): original K2 (AI materialized) + K3.
// ---------------------------------------------------------------------------
#define BPG  8
#define RPB  (NPG / BPG)    // 125
#define ECAP 1280

__global__ __launch_bounds__(256) void k_aggregate(
    const float* __restrict__ I, const int* __restrict__ erow,
    const int* __restrict__ ecol, float* __restrict__ AI)
{
    __shared__ int cnt[RPB];
    __shared__ int wp[RPB];
    __shared__ int scan[256];
    __shared__ int cols[ECAP];

    const int g     = blockIdx.x / BPG;
    const int q     = blockIdx.x % BPG;
    const int row0  = q * RPB;
    const int nbase = g * NPG;
    const int ebase = g * (NPG * DEG);
    const int tid   = threadIdx.x;

    if (tid < RPB) cnt[tid] = 0;
    __syncthreads();

    for (int e = tid; e < NPG * DEG; e += 256) {
        int rl = erow[ebase + e] - nbase - row0;
        if ((unsigned)rl < (unsigned)RPB) atomicAdd(&cnt[rl], 1);
    }
    __syncthreads();

    int v = (tid < RPB) ? cnt[tid] : 0;
    scan[tid] = v;
    __syncthreads();
    #pragma unroll
    for (int s = 1; s < 256; s <<= 1) {
        int t = (tid >= s) ? scan[tid - s] : 0;
        __syncthreads();
        scan[tid] += t;
        __syncthreads();
    }
    if (tid < RPB) wp[tid] = scan[tid] - cnt[tid];
    __syncthreads();

    for (int e = tid; e < NPG * DEG; e += 256) {
        int rl = erow[ebase + e] - nbase - row0;
        if ((unsigned)rl < (unsigned)RPB) {
            int p = atomicAdd(&wp[rl], 1);
            if (p < ECAP) cols[p] = ecol[ebase + e];
        }
    }
    __syncthreads();

    const int wave = tid >> 6, lane = tid & 63;
    const int c = lane * 2;
    for (int n = wave; n < RPB; n += 4) {
        int deg = cnt[n];
        int end = wp[n];
        int j   = end - deg;
        float ax = 0.f, ay = 0.f;
        for (; j + 4 <= end; j += 4) {
            int c0 = cols[j], c1 = cols[j + 1], c2 = cols[j + 2], c3 = cols[j + 3];
            float2 v0 = *reinterpret_cast<const float2*>(&I[(size_t)c0 * HID + c]);
            float2 v1 = *reinterpret_cast<const float2*>(&I[(size_t)c1 * HID + c]);
            float2 v2 = *reinterpret_cast<const float2*>(&I[(size_t)c2 * HID + c]);
            float2 v3 = *reinterpret_cast<const float2*>(&I[(size_t)c3 * HID + c]);
            ax += v0.x + v1.x + v2.x + v3.x;
            ay += v0.y + v1.y + v2.y + v3.y;
        }
        for (; j < end; j++) {
            float2 v0 = *reinterpret_cast<const float2*>(&I[(size_t)cols[j] * HID + c]);
            ax += v0.x; ay += v0.y;
        }
        float2 o; o.x = ax; o.y = ay;
        *reinterpret_cast<float2*>(&AI[(size_t)(nbase + row0 + n) * HID + c]) = o;
    }
}

__global__ __launch_bounds__(256) void k_final(
    const float* __restrict__ x, const float* __restrict__ lnw,
    const float* __restrict__ lnb, float* __restrict__ out)
{
    const int wave = threadIdx.x >> 6;
    const int lane = threadIdx.x & 63;
    const size_t i = (size_t)blockIdx.x * 4 + wave;
    const int c    = lane * 2;
    const size_t N = NNODES;

    float2 S  = *reinterpret_cast<const float2*>(&out[i * HID + c]);
    float2 I2 = *reinterpret_cast<const float2*>(&out[(N + i) * HID + c]);
    float2 A  = *reinterpret_cast<const float2*>(&out[(2 * N + i) * HID + c]);

    const float beta = x[(3 * N + i) * HID + 0];
    const float gam  = x[(3 * N + i) * HID + 1];

    float2 dS, dI, dR;
    dS.x = -beta * (A.x * S.x);
    dS.y = -beta * (A.y * S.y);
    dI.x = -dS.x - gam * I2.x;
    dI.y = -dS.y - gam * I2.y;
    dR.x = gam * I2.x;
    dR.y = gam * I2.y;

    const float2 lw = *reinterpret_cast<const float2*>(&lnw[c]);
    const float2 lb = *reinterpret_cast<const float2*>(&lnb[c]);

    auto ln_store = [&](float2 v, float* dst) {
        float s = v.x + v.y;
        #pragma unroll
        for (int m = 1; m < 64; m <<= 1) s += __shfl_xor(s, m);
        const float mean = s * (1.f / 128.f);
        const float dx = v.x - mean, dy = v.y - mean;
        float q = dx * dx + dy * dy;
        #pragma unroll
        for (int m = 1; m < 64; m <<= 1) q += __shfl_xor(q, m);
        const float rs = rsqrtf(q * (1.f / 128.f) + LN_EPS);
        float2 o;
        o.x = dx * rs * lw.x + lb.x;
        o.y = dy * rs * lw.y + lb.y;
        *reinterpret_cast<float2*>(dst) = o;
    };

    ln_store(dS, &out[i * HID + c]);
    ln_store(dI, &out[(N + i) * HID + c]);
    ln_store(dR, &out[(2 * N + i) * HID + c]);

    const float2 t2 =
        *reinterpret_cast<const float2*>(&x[(3 * N + i) * HID + c]);
    *reinterpret_cast<float2*>(&out[(3 * N + i) * HID + c]) = t2;
}

// ---------------------------------------------------------------------------
extern "C" void kernel_launch(void* const* d_in, const int* in_sizes, int n_in,
                              void* d_out, int out_size, void* d_ws,
                              size_t ws_size, hipStream_t stream)
{
    // inputs: 0:t 1:x 2:edge_row 3:edge_col 4:W 5:b 6:ln_w 7:ln_b
    const float* x   = (const float*)d_in[1];
    const int* erow  = (const int*)d_in[2];
    const int* ecol  = (const int*)d_in[3];
    const float* W   = (const float*)d_in[4];
    const float* b   = (const float*)d_in[5];
    const float* lnw = (const float*)d_in[6];
    const float* lnb = (const float*)d_in[7];
    float* out = (float*)d_out;

    const int nrows = 2 * NNODES;                    // R rows never needed
    const size_t ineed = (size_t)NNODES * HID * sizeof(float);

    if (d_ws != nullptr && ws_size >= ineed) {
        // Fused path: I rows -> workspace; AI never materialized.
        float* Iws = (float*)d_ws;
        k_gemm_relu<<<(nrows + K1_ROWS - 1) / K1_ROWS, 256, 0, stream>>>(
            x, W, b, out, Iws, nrows);
        k_agg_final<<<NGRAPH * BPG2, 256, 0, stream>>>(
            x, out, Iws, erow, ecol, lnw, lnb, out);
    } else {
        // Fallback: original 3-kernel path, I rows in out[N..2N).
        float* Iptr  = out + (size_t)NNODES * HID;
        float* AIptr = out + (size_t)2 * NNODES * HID;
        k_gemm_relu<<<(nrows + K1_ROWS - 1) / K1_ROWS, 256, 0, stream>>>(
            x, W, b, out, Iptr, nrows);
        k_aggregate<<<NGRAPH * BPG, 256, 0, stream>>>(Iptr, erow, ecol, AIptr);
        k_final<<<NNODES / 4, 256, 0, stream>>>(x, lnw, lnb, out);
    }
}